// Round 9
// baseline (683.057 us; speedup 1.0000x reference)
//
#include <hip/hip_runtime.h>
#include <cstdint>

#define K_IN   4096
#define N_OUT  4096
#define M_ROWS 16384
#define RANK   8
#define LSCALE 1.0f    // alpha/rank = 8/8
#define NT     64      // K_IN / 64  (BK=64 K-tiles)
#define ROWB   8192    // K_IN * 2 bytes per global row
#define AHALF  1048576 // 128 rows * ROWB

typedef __attribute__((ext_vector_type(8))) short  short8;
typedef __attribute__((ext_vector_type(4))) float  floatx4;

__device__ __forceinline__ unsigned short f2bf(float f) {
  uint32_t u = __float_as_uint(f);
  u += 0x7FFFu + ((u >> 16) & 1u);
  return (unsigned short)(u >> 16);
}

__global__ __launch_bounds__(256) void fold_w_kernel(
    const float* __restrict__ W, const float* __restrict__ lA,
    const float* __restrict__ lB, unsigned short* __restrict__ Weff) {
  int idx = blockIdx.x * 256 + threadIdx.x;
  int o = idx >> 10;
  int k = (idx & 1023) << 2;
  float4 w = *reinterpret_cast<const float4*>(W + (size_t)o * K_IN + k);
#pragma unroll
  for (int r = 0; r < RANK; ++r) {
    float s = LSCALE * lB[o * RANK + r];
    float4 a = *reinterpret_cast<const float4*>(lA + r * K_IN + k);
    w.x += s * a.x; w.y += s * a.y; w.z += s * a.z; w.w += s * a.w;
  }
  ushort4 p;
  p.x = f2bf(w.x); p.y = f2bf(w.y); p.z = f2bf(w.z); p.w = f2bf(w.w);
  *reinterpret_cast<ushort4*>(Weff + (size_t)o * K_IN + k) = p;
}

__global__ __launch_bounds__(256) void cvt_x_kernel(
    const float* __restrict__ x, unsigned short* __restrict__ xb) {
  size_t i = ((size_t)blockIdx.x * 256 + threadIdx.x) * 8;
  float4 a = *reinterpret_cast<const float4*>(x + i);
  float4 c = *reinterpret_cast<const float4*>(x + i + 4);
  uint4 v;
  v.x = (uint32_t)f2bf(a.x) | ((uint32_t)f2bf(a.y) << 16);
  v.y = (uint32_t)f2bf(a.z) | ((uint32_t)f2bf(a.w) << 16);
  v.z = (uint32_t)f2bf(c.x) | ((uint32_t)f2bf(c.y) << 16);
  v.w = (uint32_t)f2bf(c.z) | ((uint32_t)f2bf(c.w) << 16);
  *reinterpret_cast<uint4*>(xb + i) = v;
}

__device__ __forceinline__ void gload_lds16(const void* g, void* l) {
  __builtin_amdgcn_global_load_lds(
      (const __attribute__((address_space(1))) void*)g,
      (__attribute__((address_space(3))) void*)l, 16, 0, 0);
}

// FIXED swizzle (round 9): logical (row, cb) lives at phys byte
//   row*128 + (cb ^ ((row&7)<<4))        [full 3-bit slot spread]
// Old ((row&4)<<3) only toggled bit5 -> all 64 lanes confined to banks 0-15
// (2x LDS service, the invariant 4.0 conflicts/ds_read across R2-R8).
// With (row&7): 16-lane groups land 2-per-16B-slot over all 8 slots ->
// 8 bank-touches/bank = even = conflict-free (2-way is free, m136).
#define LDSWZ2(ROW, CB) (((ROW) << 7) | ((CB) ^ (((ROW) & 7) << 4)))
#define BAR() do { asm volatile("" ::: "memory");                         \
    __builtin_amdgcn_s_barrier();                                         \
    asm volatile("" ::: "memory"); } while (0)
#define LGKM0() asm volatile("s_waitcnt lgkmcnt(0)" ::: "memory")

// ---------------------------------------------------------------------------
// Kernel A: 256x256 tile, R8 structure (4 quadrant-phases, vmcnt(6) ledger),
// ONLY change = fixed swizzle. Covers out rows 0..8191 (mt 0..31), 512 blocks.
// Source pre-swizzle per thread: dest linear L=tid*16 (+8192) ->
//   row = tid>>3 (+64), src colbyte = ((tid&7) ^ ((tid>>3)&7)) << 4.
// ---------------------------------------------------------------------------
__global__ __launch_bounds__(512, 2) void gemm256_kernel(
    const unsigned short* __restrict__ Xb, const unsigned short* __restrict__ Wb,
    const float* __restrict__ bias, float* __restrict__ out) {
  __shared__ alignas(16) char lds[2 * 65536];   // 128 KiB

  const int tid  = threadIdx.x;
  const int wave = tid >> 6, lane = tid & 63;
  const int wr = wave >> 2, wc = wave & 3;      // 2 (M) x 4 (N) wave grid
  const int l15 = lane & 15, sq = lane >> 4;

  int bx  = blockIdx.x;                          // 512 blocks, %8==0
  int sbx = (bx & 7) * 64 + (bx >> 3);
  const int mt = sbx >> 4;   // 0..31
  const int nt = sbx & 15;   // 0..15

  const int rstg = tid >> 3;                                   // 0..63
  const int cbst = (((tid & 7) ^ ((tid >> 3) & 7)) << 4);      // fixed swz src
  const char* aBase = (const char*)Xb + (size_t)(mt * 256 + rstg) * ROWB + cbst;
  const char* bBase = (const char*)Wb + (size_t)(nt * 256 + rstg) * ROWB + cbst;

#define STAGE(H) do {                                                     \
    int th_ = (H) >> 2, hh_ = (H) & 3;                                    \
    const char* src_ = ((hh_ < 2) ? aBase + (size_t)hh_ * AHALF           \
                                  : bBase + (size_t)(hh_ - 2) * AHALF)    \
                       + th_ * 128;                                       \
    char* dst_ = lds + (th_ & 1) * 65536 + hh_ * 16384 + tid * 16;        \
    gload_lds16(src_, dst_);                                              \
    gload_lds16(src_ + (size_t)64 * ROWB, dst_ + 8192);                   \
  } while (0)
#define LOAD_A(DST, MQ) do {                                              \
    const char* Ab_ = lds + tb + wr * 16384;                              \
    _Pragma("unroll")                                                     \
    for (int ks = 0; ks < 2; ++ks)                                        \
      _Pragma("unroll")                                                   \
      for (int fi = 0; fi < 4; ++fi) {                                    \
        int row_ = (MQ) * 64 + fi * 16 + l15;                             \
        int cb_  = ks * 64 + sq * 16;                                     \
        DST[ks * 4 + fi] =                                                \
            *reinterpret_cast<const short8*>(Ab_ + LDSWZ2(row_, cb_));    \
      } } while (0)
#define LOAD_B(DST, NQ) do {                                              \
    const char* Bb_ = lds + tb + (2 + (wc >> 1)) * 16384;                 \
    _Pragma("unroll")                                                     \
    for (int ks = 0; ks < 2; ++ks)                                        \
      _Pragma("unroll")                                                   \
      for (int fj = 0; fj < 2; ++fj) {                                    \
        int row_ = (wc & 1) * 64 + (NQ) * 32 + fj * 16 + l15;             \
        int cb_  = ks * 64 + sq * 16;                                     \
        DST[ks * 2 + fj] =                                                \
            *reinterpret_cast<const short8*>(Bb_ + LDSWZ2(row_, cb_));    \
      } } while (0)
#define MFMA_Q(MQ, NQ, AF, BF) do {                                       \
    __builtin_amdgcn_s_setprio(1);                                        \
    _Pragma("unroll")                                                     \
    for (int ks = 0; ks < 2; ++ks)                                        \
      _Pragma("unroll")                                                   \
      for (int fi = 0; fi < 4; ++fi)                                      \
        _Pragma("unroll")                                                 \
        for (int fj = 0; fj < 2; ++fj)                                    \
          acc[(MQ) * 4 + fi][(NQ) * 2 + fj] =                             \
              __builtin_amdgcn_mfma_f32_16x16x32_bf16(                    \
                  AF[ks * 4 + fi], BF[ks * 2 + fj],                       \
                  acc[(MQ) * 4 + fi][(NQ) * 2 + fj], 0, 0, 0);            \
    __builtin_amdgcn_s_setprio(0); } while (0)

  floatx4 acc[8][4];
#pragma unroll
  for (int i = 0; i < 8; ++i)
#pragma unroll
    for (int j = 0; j < 4; ++j)
      acc[i][j] = (floatx4){0.f, 0.f, 0.f, 0.f};

  for (int h = 0; h < 7; ++h) STAGE(h);
  asm volatile("s_waitcnt vmcnt(6)" ::: "memory");
  BAR();

  short8 afA[8], afB[8], bfC[4];

  for (int t = 0; t < NT; ++t) {
    const int tb = (t & 1) * 65536;
    const int p0 = 4 * t;

    LOAD_A(afA, 0);
    LOAD_B(bfC, 0);
    if (p0 + 7 < 4 * NT) STAGE(p0 + 7);
    BAR();
    MFMA_Q(0, 0, afA, bfC);
    BAR();

    LOAD_A(afB, 1);
    if (p0 + 8 < 4 * NT) STAGE(p0 + 8);
    BAR();
    MFMA_Q(1, 0, afB, bfC);
    BAR();

    LOAD_B(bfC, 1);
    if (p0 + 9 < 4 * NT) STAGE(p0 + 9);
    BAR();
    MFMA_Q(1, 1, afB, bfC);
    BAR();

    if (p0 + 10 < 4 * NT) STAGE(p0 + 10);
    if (t <= NT - 3)      asm volatile("s_waitcnt vmcnt(6)" ::: "memory");
    else if (t == NT - 2) asm volatile("s_waitcnt vmcnt(0)" ::: "memory");
    BAR();
    MFMA_Q(0, 1, afA, bfC);
    BAR();
  }
#undef STAGE
#undef LOAD_A
#undef LOAD_B
#undef MFMA_Q

  const int row0 = mt * 256 + wr * 128 + sq * 4;
  const int col0 = nt * 256 + wc * 64 + l15;
#pragma unroll
  for (int j = 0; j < 4; ++j) {
    int col = col0 + j * 16;
    float bv = bias[col];
#pragma unroll
    for (int i = 0; i < 8; ++i) {
      int rowb = row0 + i * 16;
#pragma unroll
      for (int rr = 0; rr < 4; ++rr)
        out[(size_t)(rowb + rr) * N_OUT + col] = acc[i][j][rr] + bv;
    }
  }
}

// ---------------------------------------------------------------------------
// Kernel B: 128x128 tile, 256 threads (4 waves 2Mx2N, wave-tile 64x64),
// BK=64, dbuf LDS 2x32KB = 64KB -> 2 BLOCKS/CU (TLP: each SIMD gets one wave
// from EACH block; when one block stalls at barrier/lgkm, the other's wave
// issues MFMA — the m97 overlap mechanism, now with fixed swizzle).
// VGPR ~170 (acc 64 + frags 64 + addr) — no min-wave launch_bounds (R7 lesson).
// Covers out rows 8192..16383 (mt 0..63), 2048 blocks.
// Per buffer: A [128][64] bf16 16KB | B 16KB. Stage = 4 gloads each.
// Ledger (8 loads per STAGE per thread, in-order):
//   prologue: STAGE(0),STAGE(1) -> vmcnt(8) retires t0 -> BAR
//   iter t: reads(t) 16xb128; lgkm0; MFMA 32; BAR   [reads serviced pre-BAR
//           -> STAGE into buf t&1 after BAR is WAR-safe for ALL waves]
//           STAGE(t+2) [8]; vmcnt(8) retires t+1 (16 outstanding -> 8); BAR
//   tails:  t=NT-2: no stage, vmcnt(0); t=NT-1: skip both.
// ---------------------------------------------------------------------------
__global__ __launch_bounds__(256) void gemm128_kernel(
    const unsigned short* __restrict__ Xb, const unsigned short* __restrict__ Wb,
    const float* __restrict__ bias, float* __restrict__ out) {
  __shared__ alignas(16) char lds[2 * 32768];   // 64 KiB -> 2 blocks/CU

  const int tid  = threadIdx.x;
  const int wave = tid >> 6, lane = tid & 63;
  const int wr = wave >> 1, wc = wave & 1;      // 2 (M) x 2 (N)
  const int l15 = lane & 15, sq = lane >> 4;

  int bx  = blockIdx.x;                          // 2048 blocks, %8==0
  int sbx = (bx & 7) * 256 + (bx >> 3);
  const int mt = sbx >> 5;   // 0..63
  const int nt = sbx & 31;   // 0..31

  const int rstg = tid >> 3;                                   // 0..31
  const int cbst = (((tid & 7) ^ ((tid >> 3) & 7)) << 4);
  const char* aBase = (const char*)Xb +
      (size_t)(8192 + mt * 128 + rstg) * ROWB + cbst;
  const char* bBase = (const char*)Wb + (size_t)(nt * 128 + rstg) * ROWB + cbst;

#define STAGE2(TT) do {                                                   \
    char* d_ = lds + ((TT) & 1) * 32768 + tid * 16;                       \
    _Pragma("unroll")                                                     \
    for (int q = 0; q < 4; ++q) {                                         \
      gload_lds16(aBase + (TT) * 128 + (size_t)(q * 32) * ROWB,           \
                  d_ + q * 4096);                                         \
      gload_lds16(bBase + (TT) * 128 + (size_t)(q * 32) * ROWB,           \
                  d_ + 16384 + q * 4096);                                 \
    } } while (0)

  floatx4 acc[4][4];
#pragma unroll
  for (int i = 0; i < 4; ++i)
#pragma unroll
    for (int j = 0; j < 4; ++j)
      acc[i][j] = (floatx4){0.f, 0.f, 0.f, 0.f};

  STAGE2(0); STAGE2(1);
  asm volatile("s_waitcnt vmcnt(8)" ::: "memory");
  BAR();

  for (int t = 0; t < NT; ++t) {
    const int tb = (t & 1) * 32768;

    short8 af[8], bf[8];
    {
      const char* Ab_ = lds + tb;
      const char* Bb_ = lds + tb + 16384;
#pragma unroll
      for (int ks = 0; ks < 2; ++ks)
#pragma unroll
        for (int f = 0; f < 4; ++f) {
          int rowA = wr * 64 + f * 16 + l15;
          int rowB = wc * 64 + f * 16 + l15;
          int cb   = ks * 64 + sq * 16;
          af[ks * 4 + f] =
              *reinterpret_cast<const short8*>(Ab_ + LDSWZ2(rowA, cb));
          bf[ks * 4 + f] =
              *reinterpret_cast<const short8*>(Bb_ + LDSWZ2(rowB, cb));
        }
    }
    LGKM0();
    __builtin_amdgcn_s_setprio(1);
#pragma unroll
    for (int ks = 0; ks < 2; ++ks)
#pragma unroll
      for (int fi = 0; fi < 4; ++fi)
#pragma unroll
        for (int fj = 0; fj < 4; ++fj)
          acc[fi][fj] = __builtin_amdgcn_mfma_f32_16x16x32_bf16(
              af[ks * 4 + fi], bf[ks * 4 + fj], acc[fi][fj], 0, 0, 0);
    __builtin_amdgcn_s_setprio(0);
    BAR();                       // all waves' reads of buf t&1 serviced

    if (t + 2 < NT) {
      STAGE2(t + 2);
      asm volatile("s_waitcnt vmcnt(8)" ::: "memory");  // certify t+1
      BAR();
    } else if (t + 1 < NT) {
      asm volatile("s_waitcnt vmcnt(0)" ::: "memory");  // certify t+1 (tail)
      BAR();
    }
  }
#undef STAGE2

  const int row0 = 8192 + mt * 128 + wr * 64 + sq * 4;
  const int col0 = nt * 128 + wc * 64 + l15;
#pragma unroll
  for (int fj = 0; fj < 4; ++fj) {
    int col = col0 + fj * 16;
    float bv = bias[col];
#pragma unroll
    for (int fi = 0; fi < 4; ++fi) {
      int rowb = row0 + fi * 16;
#pragma unroll
      for (int rr = 0; rr < 4; ++rr)
        out[(size_t)(rowb + rr) * N_OUT + col] = acc[fi][fj][rr] + bv;
    }
  }
}

// self-contained correct fallback (only if ws too small): tiled fp32
__global__ __launch_bounds__(256) void fallback_kernel(
    const float* __restrict__ x, const float* __restrict__ W,
    const float* __restrict__ bias, const float* __restrict__ lA,
    const float* __restrict__ lB, float* __restrict__ out) {
  __shared__ float Xs[64][17];
  __shared__ float Ws[64][17];
  int tid = threadIdx.x;
  int tx = tid & 15, ty = tid >> 4;
  int bm = blockIdx.y * 64, bn = blockIdx.x * 64;
  float acc[4][4] = {};
  for (int k0 = 0; k0 < K_IN; k0 += 16) {
#pragma unroll
    for (int q = 0; q < 4; ++q) {
      int flat = q * 256 + tid;
      int r = flat >> 4, c = flat & 15;
      Xs[r][c] = x[(size_t)(bm + r) * K_IN + k0 + c];
      float w = W[(size_t)(bn + r) * K_IN + k0 + c];
#pragma unroll
      for (int rr = 0; rr < RANK; ++rr)
        w += LSCALE * lB[(bn + r) * RANK + rr] * lA[rr * K_IN + k0 + c];
      Ws[r][c] = w;
    }
    __syncthreads();
#pragma unroll
    for (int kk = 0; kk < 16; ++kk) {
      float av[4], bv[4];
#pragma unroll
      for (int i = 0; i < 4; ++i) av[i] = Xs[ty * 4 + i][kk];
#pragma unroll
      for (int j = 0; j < 4; ++j) bv[j] = Ws[tx * 4 + j][kk];
#pragma unroll
      for (int i = 0; i < 4; ++i)
#pragma unroll
        for (int j = 0; j < 4; ++j) acc[i][j] += av[i] * bv[j];
    }
    __syncthreads();
  }
#pragma unroll
  for (int i = 0; i < 4; ++i)
#pragma unroll
    for (int j = 0; j < 4; ++j)
      out[(size_t)(bm + ty * 4 + i) * N_OUT + bn + tx * 4 + j] =
          acc[i][j] + bias[bn + tx * 4 + j];
}

extern "C" void kernel_launch(void* const* d_in, const int* in_sizes, int n_in,
                              void* d_out, int out_size, void* d_ws, size_t ws_size,
                              hipStream_t stream) {
  const float* x  = (const float*)d_in[0];
  const float* W  = (const float*)d_in[1];
  const float* b  = (const float*)d_in[2];
  const float* lA = (const float*)d_in[3];
  const float* lB = (const float*)d_in[4];
  float* out = (float*)d_out;

  const size_t weff_bytes = (size_t)N_OUT * K_IN * 2;    // 32 MB
  const size_t xb_bytes   = (size_t)M_ROWS * K_IN * 2;   // 128 MB

  if (ws_size >= weff_bytes + xb_bytes) {
    unsigned short* Weff = (unsigned short*)d_ws;
    unsigned short* Xb   = (unsigned short*)((char*)d_ws + weff_bytes);
    fold_w_kernel<<<(int)(((size_t)N_OUT * K_IN / 4) / 256), 256, 0, stream>>>(W, lA, lB, Weff);
    cvt_x_kernel<<<(int)(((size_t)M_ROWS * K_IN / 8) / 256), 256, 0, stream>>>(x, Xb);
    // A/B split: rows 0..8191 via 256^2 fixed-swz (512 blocks);
    //            rows 8192..16383 via 128^2 TLP fixed-swz (2048 blocks)
    gemm256_kernel<<<512, 512, 0, stream>>>(Xb, Weff, b, out);
    gemm128_kernel<<<2048, 256, 0, stream>>>(Xb, Weff, b, out);
  } else {
    dim3 grid(N_OUT / 64, M_ROWS / 64);
    fallback_kernel<<<grid, 256, 0, stream>>>(x, W, b, lA, lB, out);
  }
}

// Round 11
// 577.808 us; speedup vs baseline: 1.1822x; 1.1822x over previous
//
#include <hip/hip_runtime.h>
#include <cstdint>

#define K_IN   4096
#define N_OUT  4096
#define M_ROWS 16384
#define RANK   8
#define LSCALE 1.0f    // alpha/rank = 8/8
#define NT     64      // K_IN / 64  (BK=64 K-tiles)
#define ROWB   8192    // K_IN * 2 bytes per global row
#define AHALF  1048576 // 128 rows * ROWB

typedef __attribute__((ext_vector_type(8))) short  short8;
typedef __attribute__((ext_vector_type(4))) float  floatx4;

__device__ __forceinline__ unsigned short f2bf(float f) {
  uint32_t u = __float_as_uint(f);
  u += 0x7FFFu + ((u >> 16) & 1u);
  return (unsigned short)(u >> 16);
}

__global__ __launch_bounds__(256) void fold_w_kernel(
    const float* __restrict__ W, const float* __restrict__ lA,
    const float* __restrict__ lB, unsigned short* __restrict__ Weff) {
  int idx = blockIdx.x * 256 + threadIdx.x;
  int o = idx >> 10;
  int k = (idx & 1023) << 2;
  float4 w = *reinterpret_cast<const float4*>(W + (size_t)o * K_IN + k);
#pragma unroll
  for (int r = 0; r < RANK; ++r) {
    float s = LSCALE * lB[o * RANK + r];
    float4 a = *reinterpret_cast<const float4*>(lA + r * K_IN + k);
    w.x += s * a.x; w.y += s * a.y; w.z += s * a.z; w.w += s * a.w;
  }
  ushort4 p;
  p.x = f2bf(w.x); p.y = f2bf(w.y); p.z = f2bf(w.z); p.w = f2bf(w.w);
  *reinterpret_cast<ushort4*>(Weff + (size_t)o * K_IN + k) = p;
}

__global__ __launch_bounds__(256) void cvt_x_kernel(
    const float* __restrict__ x, unsigned short* __restrict__ xb) {
  size_t i = ((size_t)blockIdx.x * 256 + threadIdx.x) * 8;
  float4 a = *reinterpret_cast<const float4*>(x + i);
  float4 c = *reinterpret_cast<const float4*>(x + i + 4);
  uint4 v;
  v.x = (uint32_t)f2bf(a.x) | ((uint32_t)f2bf(a.y) << 16);
  v.y = (uint32_t)f2bf(a.z) | ((uint32_t)f2bf(a.w) << 16);
  v.z = (uint32_t)f2bf(c.x) | ((uint32_t)f2bf(c.y) << 16);
  v.w = (uint32_t)f2bf(c.z) | ((uint32_t)f2bf(c.w) << 16);
  *reinterpret_cast<uint4*>(xb + i) = v;
}

__device__ __forceinline__ void gload_lds16(const void* g, void* l) {
  __builtin_amdgcn_global_load_lds(
      (const __attribute__((address_space(1))) void*)g,
      (__attribute__((address_space(3))) void*)l, 16, 0, 0);
}

#define BAR() do { asm volatile("" ::: "memory");                         \
    __builtin_amdgcn_s_barrier();                                         \
    asm volatile("" ::: "memory"); } while (0)

// inline-asm LDS read: base VGPR + literal offset (HK addressing idiom).
// Rule #18: read-group is followed by lgkmcnt(0)+sched_barrier(0) before
// the consuming MFMA.
#define DSR(DST, ADDR, IMM)                                               \
  asm volatile("ds_read_b128 %0, %1 offset:%2"                            \
               : "=v"(DST) : "v"(ADDR), "i"(IMM))
#define WAIT_LDS() do {                                                   \
    asm volatile("s_waitcnt lgkmcnt(0)" ::: "memory");                    \
    __builtin_amdgcn_sched_barrier(0); } while (0)

// ---------------------------------------------------------------------------
// 256x256 tile, BK=64, 512 threads (8 waves 2Mx4N), R8 quadrant-phase
// structure + vmcnt(6) ledger (race-validated R8/R9), LDSWZ2 swizzle
// (conflict-proven R9: SQ_LDS_BANK_CONFLICT = 0.0, same lane geometry).
// R10 BUG -> R11 FIX: true offset = row*128 + ((ks*64+sq*16) ^ ((l15&7)<<4)).
// R10 put ks*64 in the ADD immediate: carry from bit6 into bit7 (row) for
// lanes with bit6 of (sq*16^X) set -> +128B mis-read -> absmax 197.
// XOR and ADD don't commute; ks must fold inside the XOR. Fix: FOUR base
// registers (A/B x ks0/ks1) with (ks*64+sq*16)^X precomputed; immediates
// are pure row terms (MQ*8192+fi*2048 / NQ*4096+fj*2048, bits >=11 only,
// carry-free). Per-tile address work = 4 v_xor (buffer parity toggle).
//   aCur[ks] = tb + wr*16384 + l15*128 + ((ks*64+sq*16) ^ ((l15&7)<<4))
//   bCur[ks] = tb + (2+(wc>>1))*16384 + (wc&1)*8192 + l15*128 + (same xor)
// Phases/ledger identical to R8: stage H[4t+7..4t+10], vmcnt(6) once per
// tile at P3 (tail: NT-2 -> vmcnt(0), NT-1 skip).
// ---------------------------------------------------------------------------
__global__ __launch_bounds__(512, 2) void gemm256_kernel(
    const unsigned short* __restrict__ Xb, const unsigned short* __restrict__ Wb,
    const float* __restrict__ bias, float* __restrict__ out) {
  __shared__ alignas(16) char lds[2 * 65536];   // 128 KiB

  const int tid  = threadIdx.x;
  const int wave = tid >> 6, lane = tid & 63;
  const int wr = wave >> 2, wc = wave & 3;      // 2 (M) x 4 (N) wave grid
  const int l15 = lane & 15, sq = lane >> 4;

  // XCD swizzle: 1024 blocks (%8==0), contiguous 128-tile chunk per XCD
  int bx  = blockIdx.x;
  int sbx = (bx & 7) * 128 + (bx >> 3);
  const int mt = sbx >> 4;   // 0..63
  const int nt = sbx & 15;   // 0..15

  // staging source pre-swizzle (proven R9): linear dest L=tid*16 ->
  // logical row tid>>3, src colbyte ((tid&7)^((tid>>3)&7))<<4
  const int rstg = tid >> 3;
  const int cbst = (((tid & 7) ^ ((tid >> 3) & 7)) << 4);
  const char* aBase = (const char*)Xb + (size_t)(mt * 256 + rstg) * ROWB + cbst;
  const char* bBase = (const char*)Wb + (size_t)(nt * 256 + rstg) * ROWB + cbst;

#define STAGE(H) do {                                                     \
    int th_ = (H) >> 2, hh_ = (H) & 3;                                    \
    const char* src_ = ((hh_ < 2) ? aBase + (size_t)hh_ * AHALF           \
                                  : bBase + (size_t)(hh_ - 2) * AHALF)    \
                       + th_ * 128;                                       \
    char* dst_ = lds + (th_ & 1) * 65536 + hh_ * 16384 + tid * 16;        \
    gload_lds16(src_, dst_);                                              \
    gload_lds16(src_ + (size_t)64 * ROWB, dst_ + 8192);                   \
  } while (0)

  // precomputed LDS read bases (32-bit local offsets; AS(3) cast is the
  // same idiom gload_lds16 has used since R2)
  const unsigned ldsb = (unsigned)(unsigned long long)
      (__attribute__((address_space(3))) char*)lds;
  const unsigned X = (unsigned)((l15 & 7) << 4);
  const unsigned aRow = ldsb + wr * 16384 + l15 * 128;
  const unsigned bRow = ldsb + (2 + (wc >> 1)) * 16384 + (wc & 1) * 8192
                        + l15 * 128;
  unsigned aCur0 = aRow + (((0u  + sq * 16) ) ^ X);
  unsigned aCur1 = aRow + (((64u + sq * 16) ) ^ X);
  unsigned bCur0 = bRow + (((0u  + sq * 16) ) ^ X);
  unsigned bCur1 = bRow + (((64u + sq * 16) ) ^ X);

#define LOAD_A(DST, MQ) do {                                              \
    _Pragma("unroll")                                                     \
    for (int fi = 0; fi < 4; ++fi)                                        \
      DSR(DST[fi],     aCur0, (MQ) * 8192 + fi * 2048);                   \
    _Pragma("unroll")                                                     \
    for (int fi = 0; fi < 4; ++fi)                                        \
      DSR(DST[4 + fi], aCur1, (MQ) * 8192 + fi * 2048);                   \
  } while (0)
#define LOAD_B(DST, NQ) do {                                              \
    _Pragma("unroll")                                                     \
    for (int fj = 0; fj < 2; ++fj)                                        \
      DSR(DST[fj],     bCur0, (NQ) * 4096 + fj * 2048);                   \
    _Pragma("unroll")                                                     \
    for (int fj = 0; fj < 2; ++fj)                                        \
      DSR(DST[2 + fj], bCur1, (NQ) * 4096 + fj * 2048);                   \
  } while (0)
#define MFMA_Q(MQ, NQ, AF, BF) do {                                       \
    __builtin_amdgcn_s_setprio(1);                                        \
    _Pragma("unroll")                                                     \
    for (int ks = 0; ks < 2; ++ks)                                        \
      _Pragma("unroll")                                                   \
      for (int fi = 0; fi < 4; ++fi)                                      \
        _Pragma("unroll")                                                 \
        for (int fj = 0; fj < 2; ++fj)                                    \
          acc[(MQ) * 4 + fi][(NQ) * 2 + fj] =                             \
              __builtin_amdgcn_mfma_f32_16x16x32_bf16(                    \
                  AF[ks * 4 + fi], BF[ks * 2 + fj],                       \
                  acc[(MQ) * 4 + fi][(NQ) * 2 + fj], 0, 0, 0);            \
    __builtin_amdgcn_s_setprio(0); } while (0)

  floatx4 acc[8][4];
#pragma unroll
  for (int i = 0; i < 8; ++i)
#pragma unroll
    for (int j = 0; j < 4; ++j)
      acc[i][j] = (floatx4){0.f, 0.f, 0.f, 0.f};

  for (int h = 0; h < 7; ++h) STAGE(h);
  asm volatile("s_waitcnt vmcnt(6)" ::: "memory");
  BAR();

  short8 afA[8], afB[8], bfC[4];

  for (int t = 0; t < NT; ++t) {
    const int p0 = 4 * t;

    // ---- P0: quadrant (0,0)
    LOAD_A(afA, 0);
    LOAD_B(bfC, 0);
    if (p0 + 7 < 4 * NT) STAGE(p0 + 7);
    BAR();
    WAIT_LDS();
    MFMA_Q(0, 0, afA, bfC);
    BAR();

    // ---- P1: quadrant (1,0)
    LOAD_A(afB, 1);
    if (p0 + 8 < 4 * NT) STAGE(p0 + 8);
    BAR();
    WAIT_LDS();
    MFMA_Q(1, 0, afB, bfC);
    BAR();

    // ---- P2: quadrant (1,1)
    LOAD_B(bfC, 1);
    if (p0 + 9 < 4 * NT) STAGE(p0 + 9);
    BAR();
    WAIT_LDS();
    MFMA_Q(1, 1, afB, bfC);
    BAR();

    // ---- P3: quadrant (0,1); single per-tile vmcnt cert
    if (p0 + 10 < 4 * NT) STAGE(p0 + 10);
    if (t <= NT - 3)      asm volatile("s_waitcnt vmcnt(6)" ::: "memory");
    else if (t == NT - 2) asm volatile("s_waitcnt vmcnt(0)" ::: "memory");
    BAR();
    MFMA_Q(0, 1, afA, bfC);
    BAR();

    // buffer parity toggle (the ONLY per-tile address update)
    aCur0 ^= 65536u; aCur1 ^= 65536u;
    bCur0 ^= 65536u; bCur1 ^= 65536u;
  }
#undef STAGE
#undef LOAD_A
#undef LOAD_B
#undef MFMA_Q

  // epilogue: C/D layout col=lane&15, row=(lane>>4)*4+reg (m89/m91 verified)
  const int row0 = mt * 256 + wr * 128 + sq * 4;
  const int col0 = nt * 256 + wc * 64 + l15;
#pragma unroll
  for (int j = 0; j < 4; ++j) {
    int col = col0 + j * 16;
    float bv = bias[col];
#pragma unroll
    for (int i = 0; i < 8; ++i) {
      int rowb = row0 + i * 16;
#pragma unroll
      for (int rr = 0; rr < 4; ++rr)
        out[(size_t)(rowb + rr) * N_OUT + col] = acc[i][j][rr] + bv;
    }
  }
}

// self-contained correct fallback (only if ws too small): tiled fp32
__global__ __launch_bounds__(256) void fallback_kernel(
    const float* __restrict__ x, const float* __restrict__ W,
    const float* __restrict__ bias, const float* __restrict__ lA,
    const float* __restrict__ lB, float* __restrict__ out) {
  __shared__ float Xs[64][17];
  __shared__ float Ws[64][17];
  int tid = threadIdx.x;
  int tx = tid & 15, ty = tid >> 4;
  int bm = blockIdx.y * 64, bn = blockIdx.x * 64;
  float acc[4][4] = {};
  for (int k0 = 0; k0 < K_IN; k0 += 16) {
#pragma unroll
    for (int q = 0; q < 4; ++q) {
      int flat = q * 256 + tid;
      int r = flat >> 4, c = flat & 15;
      Xs[r][c] = x[(size_t)(bm + r) * K_IN + k0 + c];
      float w = W[(size_t)(bn + r) * K_IN + k0 + c];
#pragma unroll
      for (int rr = 0; rr < RANK; ++rr)
        w += LSCALE * lB[(bn + r) * RANK + rr] * lA[rr * K_IN + k0 + c];
      Ws[r][c] = w;
    }
    __syncthreads();
#pragma unroll
    for (int kk = 0; kk < 16; ++kk) {
      float av[4], bv[4];
#pragma unroll
      for (int i = 0; i < 4; ++i) av[i] = Xs[ty * 4 + i][kk];
#pragma unroll
      for (int j = 0; j < 4; ++j) bv[j] = Ws[tx * 4 + j][kk];
#pragma unroll
      for (int i = 0; i < 4; ++i)
#pragma unroll
        for (int j = 0; j < 4; ++j) acc[i][j] += av[i] * bv[j];
    }
    __syncthreads();
  }
#pragma unroll
  for (int i = 0; i < 4; ++i)
#pragma unroll
    for (int j = 0; j < 4; ++j)
      out[(size_t)(bm + ty * 4 + i) * N_OUT + bn + tx * 4 + j] =
          acc[i][j] + bias[bn + tx * 4 + j];
}

extern "C" void kernel_launch(void* const* d_in, const int* in_sizes, int n_in,
                              void* d_out, int out_size, void* d_ws, size_t ws_size,
                              hipStream_t stream) {
  const float* x  = (const float*)d_in[0];
  const float* W  = (const float*)d_in[1];
  const float* b  = (const float*)d_in[2];
  const float* lA = (const float*)d_in[3];
  const float* lB = (const float*)d_in[4];
  float* out = (float*)d_out;

  const size_t weff_bytes = (size_t)N_OUT * K_IN * 2;    // 32 MB
  const size_t xb_bytes   = (size_t)M_ROWS * K_IN * 2;   // 128 MB

  if (ws_size >= weff_bytes + xb_bytes) {
    unsigned short* Weff = (unsigned short*)d_ws;
    unsigned short* Xb   = (unsigned short*)((char*)d_ws + weff_bytes);
    fold_w_kernel<<<(int)(((size_t)N_OUT * K_IN / 4) / 256), 256, 0, stream>>>(W, lA, lB, Weff);
    cvt_x_kernel<<<(int)(((size_t)M_ROWS * K_IN / 8) / 256), 256, 0, stream>>>(x, Xb);
    gemm256_kernel<<<(M_ROWS / 256) * (N_OUT / 256), 512, 0, stream>>>(Xb, Weff, b, out);
  } else {
    dim3 grid(N_OUT / 64, M_ROWS / 64);
    fallback_kernel<<<grid, 256, 0, stream>>>(x, W, b, lA, lB, out);
  }
}